// Round 13
// baseline (203.104 us; speedup 1.0000x reference)
//
#include <hip/hip_runtime.h>
#include <cfloat>
#include <cstdint>

// Problem constants (B=4, N=2048, C=64, O=64, K=20)
#define M_TOTAL 8192
#define KNN 20
#define PPART 8                  // candidate partitions
#define CPB (M_TOTAL / PPART)    // 1024 candidates per K1b block
#define QT1B 64                  // queries per K1b block (v10 sweet spot; v11=32 regressed)
#define QT1A 16                  // queries per K1a block
#define SAMPLE 1024              // tau sample = candidates [0, 1024)
#define CAP 64                   // collect capacity per (query,partition); E~24, 7+ sigma
#define QT2 8                    // queries per K2ab block (v7: quarter-split, 2x grid TLP)
#define KSL 32                   // slices per K2ab block: 8 partitions x 4 quarters
#define GCAP 40                  // guard cap (T <= v6's kept-20th: validated ~22/query)
#define HCAP 16                  // max keys per quarter-slice = CAP/4

typedef __attribute__((ext_vector_type(8))) short bf16x8;  // 8 bf16 (4 VGPRs)
typedef __attribute__((ext_vector_type(4))) float f32x4;

__device__ __forceinline__ unsigned short bf16rne(float x) {
  unsigned u = __float_as_uint(x);
  return (unsigned short)((u + 0x7FFFu + ((u >> 16) & 1u)) >> 16);
}

// ---------------------------------------------------------------------------
// K0: per-point precompute. sq, bf16 pos (hi only; k2ab re-ranks exact fp32),
// factored layer-1 (a, g). Blocks 0-1 also emit the W2 B-frag swizzle.
// ---------------------------------------------------------------------------
__global__ __launch_bounds__(256) void k0_pre(
    const float* __restrict__ pos, const float* __restrict__ feat,
    const float* __restrict__ W1, const float* __restrict__ b1,
    const float* __restrict__ W2,
    float* __restrict__ sq, float* __restrict__ a_out, float* __restrict__ g_out,
    unsigned short* __restrict__ poshi, unsigned short* __restrict__ w2sw) {
  __shared__ float fLds[4][64];
  const int lane = threadIdx.x & 63;
  const int rl = threadIdx.x >> 6;
  const int r = blockIdx.x * 4 + rl;

  float p = pos[r * 64 + lane];
  float f = feat[r * 64 + lane];
  fLds[rl][lane] = f;  // wave-private row; wave lockstep

  poshi[r * 64 + lane] = bf16rne(p);

  float s = p * p;
#pragma unroll
  for (int off = 1; off < 64; off <<= 1) s += __shfl_xor(s, off, 64);
  if (lane == 0) sq[r] = s;

  float acc_a = b1[lane];
  float acc_g = 0.f;
  const float4* f4 = reinterpret_cast<const float4*>(fLds[rl]);
#pragma unroll
  for (int i = 0; i < 16; ++i) {
    float4 fv = f4[i];
    float fd[4] = {fv.x, fv.y, fv.z, fv.w};
#pragma unroll
    for (int j = 0; j < 4; ++j) {
      int d = 4 * i + j;
      float wt = W1[d * 64 + lane];
      float wb = W1[(64 + d) * 64 + lane];
      acc_a = fmaf(fd[j], wt - wb, acc_a);
      acc_g = fmaf(fd[j], wb, acc_g);
    }
  }
  a_out[r * 64 + lane] = acc_a;
  g_out[r * 64 + lane] = acc_g;

  if (blockIdx.x < 2) {  // fused W2 swizzle (frag f = seg*4 + t)
    const int u = blockIdx.x * 256 + threadIdx.x;  // [0, 512)
    const int fr = u >> 6, ul = u & 63;
    const int seg = fr >> 2, t = fr & 3;
    const int uq = ul >> 4, uc = ul & 15;
#pragma unroll
    for (int j = 0; j < 8; ++j) {
      int d = seg * 32 + uq * 8 + j;
      w2sw[u * 8 + j] = bf16rne(W2[d * 64 + t * 16 + uc]);
    }
  }
}

// ---------------------------------------------------------------------------
// K1a v2 (round-9 verified): 512 blocks, 16 x top-4 streams, rank-by-count
// tau (bucket-ceiling, +0.5 margin).
// ---------------------------------------------------------------------------
__global__ __launch_bounds__(256, 4) void k1a_tau(
    const unsigned short* __restrict__ poshi,
    const float* __restrict__ sq, float* __restrict__ tau_g) {
  __shared__ float vw[4][16][20];         // [wave][cand][query+pad], 5 KiB
  __shared__ float sqcLds[SAMPLE];        // 4 KiB
  __shared__ unsigned topLds[16][4][17];  // [stream][k][query+pad], 4.25 KiB
  const int lane = threadIdx.x & 63;
  const int w = threadIdx.x >> 6;
  const int qbase = blockIdx.x * QT1A;
  const int col = lane & 15;
  const int quad = lane >> 4;
  const int dimOff = quad * 8;

  for (int i = threadIdx.x; i < SAMPLE; i += 256) sqcLds[i] = sq[i];

  bf16x8 A0 = *(const bf16x8*)(poshi + (size_t)(qbase + col) * 64 + dimOff);
  bf16x8 A1 = *(const bf16x8*)(poshi + (size_t)(qbase + col) * 64 + dimOff + 32);
  __syncthreads();  // sqcLds ready

  const f32x4 zf = {0.f, 0.f, 0.f, 0.f};
  float bd[4];
#pragma unroll
  for (int k = 0; k < 4; ++k) bd[k] = FLT_MAX;

  bf16x8 Bh0 = *(const bf16x8*)(poshi + (size_t)(w * 16 + col) * 64 + dimOff);
  bf16x8 Bh1 = *(const bf16x8*)(poshi + (size_t)(w * 16 + col) * 64 + dimOff + 32);
  for (int c0 = 0; c0 < SAMPLE; c0 += 64) {
    const int nc0 = (c0 + 64 < SAMPLE) ? c0 + 64 : c0;
    bf16x8 Nh0 = *(const bf16x8*)(poshi + (size_t)(nc0 + w * 16 + col) * 64 + dimOff);
    bf16x8 Nh1 = *(const bf16x8*)(poshi + (size_t)(nc0 + w * 16 + col) * 64 + dimOff + 32);

    f32x4 acc = zf;
    acc = __builtin_amdgcn_mfma_f32_16x16x32_bf16(A0, Bh0, acc, 0, 0, 0);
    acc = __builtin_amdgcn_mfma_f32_16x16x32_bf16(A1, Bh1, acc, 0, 0, 0);

    const float sqcv = sqcLds[c0 + w * 16 + col] + 256.0f;
    float4 v4;
    v4.x = fmaf(-2.f, acc[0], sqcv);
    v4.y = fmaf(-2.f, acc[1], sqcv);
    v4.z = fmaf(-2.f, acc[2], sqcv);
    v4.w = fmaf(-2.f, acc[3], sqcv);
    *reinterpret_cast<float4*>(&vw[w][col][quad * 4]) = v4;  // [cand][query]
    __builtin_amdgcn_wave_barrier();  // wave-private region, lockstep
#pragma unroll
    for (int i = 0; i < 4; ++i) {
      float cd = vw[w][quad * 4 + i][col];  // stream (w,quad): cands quad*4+i
#pragma unroll
      for (int k = 0; k < 4; ++k) {  // branch-free sorted insert (top-4)
        float lo = fminf(cd, bd[k]);
        cd = fmaxf(cd, bd[k]);
        bd[k] = lo;
      }
    }
    __builtin_amdgcn_wave_barrier();
    Bh0 = Nh0; Bh1 = Nh1;
  }

  // post packed keys: unique id = (stream<<2)|k in the low 13 bits
  {
    const int stream = w * 4 + quad;
#pragma unroll
    for (int k = 0; k < 4; ++k) {
      unsigned fb = __float_as_uint(bd[k]);
      topLds[stream][k][col] =
          (fb & 0xFFFFE000u) | (unsigned)(stream << 2) | (unsigned)k;
    }
  }
  __syncthreads();

  // tau = kept-20th via rank-by-counting (16 streams x 16 queries = 256 thr)
  {
    const int g = threadIdx.x >> 4;   // stream
    const int l = threadIdx.x & 15;   // query
    unsigned mk[4];
#pragma unroll
    for (int k = 0; k < 4; ++k) mk[k] = topLds[g][k][l];
    int rk[4] = {0, 0, 0, 0};
#pragma unroll
    for (int st = 0; st < 16; ++st) {
#pragma unroll
      for (int i = 0; i < 4; ++i) {
        unsigned v = topLds[st][i][l];
#pragma unroll
        for (int k = 0; k < 4; ++k) rk[k] += (v < mk[k]) ? 1 : 0;
      }
    }
#pragma unroll
    for (int k = 0; k < 4; ++k) {
      if (rk[k] == KNN - 1)  // unique rank-19 key -> single writer per query
        tau_g[qbase + l] =
            __uint_as_float((mk[k] & 0xFFFFE000u) + 0x2000u) + 0.5f;
    }
  }
}

// ---------------------------------------------------------------------------
// K1b v10 (round-4/10/12 verified): QT1B=64 -> 1024 blocks x 4 waves,
// VGPR 80, no spills. QT1B=32 (v11) regressed — do not re-split.
// ---------------------------------------------------------------------------
__global__ __launch_bounds__(256, 4) void k1b_collect(
    const unsigned short* __restrict__ poshi,
    const float* __restrict__ sq, const float* __restrict__ tau_g,
    unsigned* __restrict__ list, unsigned* __restrict__ cnt_ws) {
  __shared__ float sqcLds[CPB];      // 4 KiB
  __shared__ float tauLds[QT1B];
  __shared__ unsigned cntLds[QT1B];

  const int lane = threadIdx.x & 63;
  const int w = threadIdx.x >> 6;    // 0..3
  const int qbase = blockIdx.x * QT1B;
  const int cbase = blockIdx.y * CPB;
  const int col = lane & 15;
  const int quad = lane >> 4;
  const int dimOff = quad * 8;

  for (int i = threadIdx.x; i < CPB; i += 256) sqcLds[i] = sq[cbase + i];
  if (threadIdx.x < QT1B) {
    tauLds[threadIdx.x] = tau_g[qbase + threadIdx.x];
    cntLds[threadIdx.x] = 0;
  }

  // A-fragments: 4 groups of 16 queries (loaded once, reused for 16 stripes)
  bf16x8 Ahi[4][2];
#pragma unroll
  for (int s = 0; s < 4; ++s) {
    int row = qbase + s * 16 + col;
    Ahi[s][0] = *(const bf16x8*)(poshi + (size_t)row * 64 + dimOff);
    Ahi[s][1] = *(const bf16x8*)(poshi + (size_t)row * 64 + dimOff + 32);
  }
  __syncthreads();

  float tau_l[4][4];
#pragma unroll
  for (int s = 0; s < 4; ++s)
#pragma unroll
    for (int r = 0; r < 4; ++r) tau_l[s][r] = tauLds[s * 16 + quad * 4 + r];

  const f32x4 zf = {0.f, 0.f, 0.f, 0.f};
  bf16x8 Bh0 = *(const bf16x8*)(poshi + (size_t)(cbase + w * 16 + col) * 64 + dimOff);
  bf16x8 Bh1 = *(const bf16x8*)(poshi + (size_t)(cbase + w * 16 + col) * 64 + dimOff + 32);
  for (int c0 = 0; c0 < CPB; c0 += 64) {
    const int nc0 = (c0 + 64 < CPB) ? c0 + 64 : c0;
    bf16x8 Nh0 = *(const bf16x8*)(poshi + (size_t)(cbase + nc0 + w * 16 + col) * 64 + dimOff);
    bf16x8 Nh1 = *(const bf16x8*)(poshi + (size_t)(cbase + nc0 + w * 16 + col) * 64 + dimOff + 32);

    f32x4 acc[4] = {zf, zf, zf, zf};
#pragma unroll
    for (int s = 0; s < 4; ++s) {
      acc[s] = __builtin_amdgcn_mfma_f32_16x16x32_bf16(Ahi[s][0], Bh0, acc[s], 0, 0, 0);
      acc[s] = __builtin_amdgcn_mfma_f32_16x16x32_bf16(Ahi[s][1], Bh1, acc[s], 0, 0, 0);
    }
    const int candRow = cbase + c0 + w * 16 + col;
    const float sqcv = sqcLds[c0 + w * 16 + col] + 256.0f;
#pragma unroll
    for (int s = 0; s < 4; ++s) {
#pragma unroll
      for (int r = 0; r < 4; ++r) {
        float val = fmaf(-2.f, acc[s][r], sqcv);
        const int qrow = s * 16 + quad * 4 + r;  // D row = quad*4+reg
        if (val <= tau_l[s][r]) {  // ~2% of lanes
          unsigned slot = atomicAdd(&cntLds[qrow], 1u);
          if (slot < CAP)
            list[(size_t)(blockIdx.y * CAP + slot) * M_TOTAL + qbase + qrow] =
                (__float_as_uint(val) & 0xFFFFE000u) | (unsigned)candRow;
        }
      }
    }
    Bh0 = Nh0; Bh1 = Nh1;
  }
  __syncthreads();
  if (threadIdx.x < QT1B) {
    unsigned c = cntLds[threadIdx.x];
    cnt_ws[blockIdx.y * M_TOTAL + qbase + threadIdx.x] = c > CAP ? CAP : c;
  }
}

// ---------------------------------------------------------------------------
// K2ab v7: quarter-split. 8 queries x 32 slices (8 partitions x 4 quarters),
// grid 1024 -> 4 blocks/CU (LDS ~36 KiB), 16 waves/CU = 2x v6's TLP.
// Merges stay rank-by-counting (cost per thread ~constant in slice count;
// round-5's serial-merge trap does not apply). Safety: quarter-kept union
// SUPERSET of half-kept union => T_v7 <= T_v6 => guard <= validated ~22
// << GCAP 40. Phase 1 stashes keys in kLds; phase 3 rescans from LDS (v6).
// ---------------------------------------------------------------------------
__global__ __launch_bounds__(256) void k2ab(
    const float* __restrict__ pos, const float* __restrict__ sq,
    const unsigned* __restrict__ list, const unsigned* __restrict__ cnt_ws,
    const float* __restrict__ a_in, const float* __restrict__ g_in,
    const unsigned short* __restrict__ w2sw, const float* __restrict__ b2,
    float* __restrict__ out) {
  __shared__ unsigned kLds[KSL][QT2][HCAP + 1];       // scanned keys, 17.4 KiB
  __shared__ unsigned topLds[KSL][QT2][9];            // kept keys, 9.2 KiB
  __shared__ unsigned cntSl[KSL][QT2];                // 1 KiB
  __shared__ unsigned TLds[QT2];
  __shared__ unsigned ccnt[QT2];
  __shared__ unsigned candLds[QT2][GCAP];             // 1.3 KiB
  __shared__ unsigned long long rrLds[KSL][QT2][3];   // 2 used + pad, 6.1 KiB
  __shared__ int nbrLds[QT2][KNN];                    // 0.64 KiB

  const int l = threadIdx.x & 7;     // query lane 0..7
  const int s2 = threadIdx.x >> 3;   // slice 0..31
  const int sp = s2 >> 2;            // partition 0..7
  const int qt = s2 & 3;             // quarter of the slot range
  const int q = blockIdx.x * QT2 + l;

  // ---- phase 1: per-slice top-8 over this quarter's keys; stash in LDS ----
  unsigned bd[8];
#pragma unroll
  for (int k = 0; k < 8; ++k) bd[k] = 0xFFFFFFFFu;
  const unsigned c = cnt_ws[sp * M_TOTAL + q];
  const unsigned ch = (c > (unsigned)qt) ? ((c - (unsigned)qt + 3u) >> 2) : 0u;
  const unsigned* base = list + (size_t)(sp * CAP) * M_TOTAL + q;
  for (unsigned sl0 = 0; sl0 < ch; sl0 += 8) {
    unsigned kk[8];
#pragma unroll
    for (int j = 0; j < 8; ++j) {
      unsigned slj = sl0 + j;
      unsigned eff = slj < ch ? slj : 0u;          // safe: ch>0 inside loop
      kk[j] = base[(size_t)(qt + 4u * eff) * M_TOTAL];
    }
#pragma unroll
    for (int j = 0; j < 8; ++j) {
      unsigned cd;
      if (sl0 + j < ch) {
        kLds[s2][l][sl0 + j] = kk[j];  // stash for phase 3 (same thread)
        cd = kk[j];
      } else {
        cd = 0xFFFFFFFFu;
      }
#pragma unroll
      for (int k = 0; k < 8; ++k) {
        unsigned lo = cd < bd[k] ? cd : bd[k];
        cd = cd < bd[k] ? bd[k] : cd;
        bd[k] = lo;
      }
    }
  }
#pragma unroll
  for (int k = 0; k < 8; ++k) topLds[s2][l][k] = bd[k];
  cntSl[s2][l] = (ch < 8u) ? ch : 8u;
  __syncthreads();

  // ---- phase 2a: baseline T (fallback), init counters ----
  if (threadIdx.x < QT2) {
    unsigned kt = 0;
#pragma unroll
    for (int st = 0; st < KSL; ++st) kt += cntSl[st][l];
    TLds[l] = (kt >= (unsigned)KNN) ? 0u : 0xFFFFFFFFu;  // overwritten below if >=20
    ccnt[l] = 0;
#pragma unroll
    for (int k = 0; k < KNN; ++k) nbrLds[l][k] = 0;  // guard (cc<20 ~impossible)
  }
  __syncthreads();

  // ---- phase 2b: T = kept-20th via rank-by-counting over 256 keys ----
  {
    int rk[8] = {0, 0, 0, 0, 0, 0, 0, 0};
#pragma unroll
    for (int st = 0; st < KSL; ++st) {
#pragma unroll
      for (int i = 0; i < 8; ++i) {
        unsigned v = topLds[st][l][i];
#pragma unroll
        for (int k = 0; k < 8; ++k) rk[k] += (v < bd[k]) ? 1 : 0;
      }
    }
#pragma unroll
    for (int k = 0; k < 8; ++k) {
      if (bd[k] != 0xFFFFFFFFu && rk[k] == KNN - 1)
        TLds[l] = (bd[k] >> 13) + 3;  // unique rank-19 key -> single writer
    }
  }
  __syncthreads();

  // ---- phase 3: rescan this quarter's keys FROM LDS, collect guard set ----
  const unsigned T = TLds[l];
  for (unsigned j = 0; j < ch; ++j) {
    unsigned key = kLds[s2][l][j];
    if ((key >> 13) <= T) {
      unsigned pos_ = atomicAdd(&ccnt[l], 1u);
      if (pos_ < GCAP) candLds[l][pos_] = key & 0x1FFFu;
    }
  }
  __syncthreads();

  // ---- phase 4: exact fp32 d2 re-rank; sorted-2 per thread ----
  const int cc = min(ccnt[l], (unsigned)GCAP);
  const float sqq = sq[q];
  const float4* qp4 = reinterpret_cast<const float4*>(pos + (size_t)q * 64);
  unsigned long long kb[2];
#pragma unroll
  for (int j = 0; j < 2; ++j) kb[j] = ~0ull;
  for (int j = s2; j < cc; j += KSL) {  // <= ceil(40/32) = 2 candidates
    const unsigned idx = candLds[l][j];
    const float4* cp4 = reinterpret_cast<const float4*>(pos + (size_t)idx * 64);
    float d0 = 0.f, d1 = 0.f, d2 = 0.f, d3 = 0.f;
#pragma unroll
    for (int t = 0; t < 16; ++t) {
      float4 cv = cp4[t];
      float4 qv = qp4[t];  // L1/L2-hot
      d0 = fmaf(cv.x, qv.x, d0);
      d1 = fmaf(cv.y, qv.y, d1);
      d2 = fmaf(cv.z, qv.z, d2);
      d3 = fmaf(cv.w, qv.w, d3);
    }
    float dot = (d0 + d1) + (d2 + d3);
    float dd = fmaxf(fmaf(-2.f, dot, sqq + sq[idx]), 0.f);
    unsigned long long cd = ((unsigned long long)__float_as_uint(dd) << 32) | idx;
#pragma unroll
    for (int k = 0; k < 2; ++k) {  // sorted-2 insert (tie -> smaller idx)
      unsigned long long lo = cd < kb[k] ? cd : kb[k];
      cd = cd < kb[k] ? kb[k] : cd;
      kb[k] = lo;
    }
  }
#pragma unroll
  for (int j = 0; j < 2; ++j) rrLds[s2][l][j] = kb[j];
  __syncthreads();

  // ---- rank-by-counting top-20 placement over 64 exact keys ----
  {
    int rk[2] = {0, 0};
#pragma unroll
    for (int st = 0; st < KSL; ++st) {
#pragma unroll
      for (int i = 0; i < 2; ++i) {
        unsigned long long v = rrLds[st][l][i];
#pragma unroll
        for (int j = 0; j < 2; ++j) rk[j] += (v < kb[j]) ? 1 : 0;
      }
    }
#pragma unroll
    for (int j = 0; j < 2; ++j) {
      if (kb[j] != ~0ull && rk[j] < KNN)
        nbrLds[l][rk[j]] = (int)(unsigned)(kb[j] & 0xFFFFFFFFu);
    }
  }
  __syncthreads();

  // ---- phase 5: MLP + max-agg via MFMA, 4 waves x 2 rounds (8 queries) ----
  const int lane = threadIdx.x & 63;
  const int wv = threadIdx.x >> 6;
  const int col = lane & 15;
  const int quad = lane >> 4;

  bf16x8 Bf[8];
#pragma unroll
  for (int f = 0; f < 8; ++f)
    Bf[f] = *(const bf16x8*)(w2sw + ((size_t)f * 64 + lane) * 8);
  const float bias = b2[lane];

  for (int t = 0; t < 2; ++t) {
    const int li = t * 4 + wv;                 // local query 0..7
    const int q2 = blockIdx.x * QT2 + li;
    const int n0 = nbrLds[li][col];
    const int n1 = nbrLds[li][(16 + col) % KNN];

    const f32x4 zf = {0.f, 0.f, 0.f, 0.f};
    f32x4 acc0[4] = {zf, zf, zf, zf};
    f32x4 acc1[4] = {zf, zf, zf, zf};
#pragma unroll
    for (int seg = 0; seg < 2; ++seg) {
      const int dOff = seg * 32 + quad * 8;
      const float4* ap = reinterpret_cast<const float4*>(a_in + (size_t)q2 * 64 + dOff);
      const float4* g0p = reinterpret_cast<const float4*>(g_in + (size_t)n0 * 64 + dOff);
      const float4* g1p = reinterpret_cast<const float4*>(g_in + (size_t)n1 * 64 + dOff);
      float4 aa0 = ap[0], aa1 = ap[1];
      float4 gg0 = g0p[0], gg1 = g0p[1];
      float4 hh0 = g1p[0], hh1 = g1p[1];
      float av[8] = {aa0.x, aa0.y, aa0.z, aa0.w, aa1.x, aa1.y, aa1.z, aa1.w};
      float g0v[8] = {gg0.x, gg0.y, gg0.z, gg0.w, gg1.x, gg1.y, gg1.z, gg1.w};
      float g1v[8] = {hh0.x, hh0.y, hh0.z, hh0.w, hh1.x, hh1.y, hh1.z, hh1.w};
      bf16x8 A0, A1;
#pragma unroll
      for (int j = 0; j < 8; ++j) {
        A0[j] = (short)bf16rne(fmaxf(av[j] + g0v[j], 0.f));
        A1[j] = (short)bf16rne(fmaxf(av[j] + g1v[j], 0.f));
      }
#pragma unroll
      for (int tt = 0; tt < 4; ++tt) {
        acc0[tt] = __builtin_amdgcn_mfma_f32_16x16x32_bf16(A0, Bf[seg * 4 + tt], acc0[tt], 0, 0, 0);
        acc1[tt] = __builtin_amdgcn_mfma_f32_16x16x32_bf16(A1, Bf[seg * 4 + tt], acc1[tt], 0, 0, 0);
      }
    }
    float res = 0.f;
#pragma unroll
    for (int tt = 0; tt < 4; ++tt) {
      float m = fmaxf(fmaxf(fmaxf(acc0[tt][0], acc1[tt][0]), fmaxf(acc0[tt][1], acc1[tt][1])),
                      fmaxf(fmaxf(acc0[tt][2], acc1[tt][2]), fmaxf(acc0[tt][3], acc1[tt][3])));
      m = fmaxf(m, __shfl_xor(m, 16, 64));
      m = fmaxf(m, __shfl_xor(m, 32, 64));
      res = (quad == tt) ? m : res;  // o = tt*16+col == lane iff quad==tt
    }
    out[(size_t)q2 * 64 + lane] = res + bias;
  }
}

// ---------------------------------------------------------------------------
extern "C" void kernel_launch(void* const* d_in, const int* in_sizes, int n_in,
                              void* d_out, int out_size, void* d_ws, size_t ws_size,
                              hipStream_t stream) {
  const float* pos = (const float*)d_in[0];
  const float* feat = (const float*)d_in[1];
  const float* W1 = (const float*)d_in[2];
  const float* b1 = (const float*)d_in[3];
  const float* W2 = (const float*)d_in[4];
  const float* b2 = (const float*)d_in[5];
  float* out = (float*)d_out;

  // ws layout (bytes), total ~23.3 MiB:
  //   sq    @ 0         32 KiB
  //   a     @ 32768     2 MiB
  //   g     @ 2129920   2 MiB
  //   poshi @ 4227072   1 MiB
  //   w2sw  @ 6324224   8 KiB
  //   list  @ 6332416   16 MiB  (512 slots x 8192 queries, transposed u32 keys)
  //   cnt   @ 23109632  256 KiB (8 x 8192, transposed)
  //   tau   @ 23633920  32 KiB
  char* ws = (char*)d_ws;
  float* sq = (float*)ws;
  float* a = (float*)(ws + 32768);
  float* g = (float*)(ws + 2129920);
  unsigned short* poshi = (unsigned short*)(ws + 4227072);
  unsigned short* w2sw = (unsigned short*)(ws + 6324224);
  unsigned* list = (unsigned*)(ws + 6332416);
  unsigned* cnt_ws = (unsigned*)(ws + 23109632);
  float* tau_g = (float*)(ws + 23633920);

  k0_pre<<<M_TOTAL / 4, 256, 0, stream>>>(pos, feat, W1, b1, W2, sq, a, g, poshi, w2sw);
  k1a_tau<<<M_TOTAL / QT1A, 256, 0, stream>>>(poshi, sq, tau_g);
  k1b_collect<<<dim3(M_TOTAL / QT1B, PPART), 256, 0, stream>>>(poshi, sq, tau_g, list, cnt_ws);
  k2ab<<<M_TOTAL / QT2, 256, 0, stream>>>(pos, sq, list, cnt_ws, a, g, w2sw, b2, out);
}

// Round 14
// 156.493 us; speedup vs baseline: 1.2979x; 1.2979x over previous
//
#include <hip/hip_runtime.h>
#include <cfloat>
#include <cstdint>

// Problem constants (B=4, N=2048, C=64, O=64, K=20)
#define M_TOTAL 8192
#define KNN 20
#define PPART 8                  // candidate partitions
#define CPB (M_TOTAL / PPART)    // 1024 candidates per K1b block
#define QT1B 64                  // queries per K1b block (v10 sweet spot; v11=32 regressed)
#define QT1A 16                  // queries per K1a block
#define SAMPLE 1024              // tau sample = candidates [0, 1024)
#define CAP 64                   // collect capacity per (query,partition); E~24, 7+ sigma
#define QT2 16                   // queries per K2ab block (v6 sweet spot; v7=8 regressed)
#define KSL 16                   // slices per K2ab block: 8 partitions x 2 halves
#define GCAP 40                  // guard cap (T <= v4's kept-20th: validated ~22/query)
#define HCAP 32                  // max keys per half-slice = CAP/2

typedef __attribute__((ext_vector_type(8))) short bf16x8;  // 8 bf16 (4 VGPRs)
typedef __attribute__((ext_vector_type(4))) float f32x4;

__device__ __forceinline__ unsigned short bf16rne(float x) {
  unsigned u = __float_as_uint(x);
  return (unsigned short)((u + 0x7FFFu + ((u >> 16) & 1u)) >> 16);
}

// ---------------------------------------------------------------------------
// K0: per-point precompute. sq, bf16 pos (hi only; k2ab re-ranks exact fp32),
// factored layer-1 (a, g). Blocks 0-1 also emit the W2 B-frag swizzle.
// ---------------------------------------------------------------------------
__global__ __launch_bounds__(256) void k0_pre(
    const float* __restrict__ pos, const float* __restrict__ feat,
    const float* __restrict__ W1, const float* __restrict__ b1,
    const float* __restrict__ W2,
    float* __restrict__ sq, float* __restrict__ a_out, float* __restrict__ g_out,
    unsigned short* __restrict__ poshi, unsigned short* __restrict__ w2sw) {
  __shared__ float fLds[4][64];
  const int lane = threadIdx.x & 63;
  const int rl = threadIdx.x >> 6;
  const int r = blockIdx.x * 4 + rl;

  float p = pos[r * 64 + lane];
  float f = feat[r * 64 + lane];
  fLds[rl][lane] = f;  // wave-private row; wave lockstep

  poshi[r * 64 + lane] = bf16rne(p);

  float s = p * p;
#pragma unroll
  for (int off = 1; off < 64; off <<= 1) s += __shfl_xor(s, off, 64);
  if (lane == 0) sq[r] = s;

  float acc_a = b1[lane];
  float acc_g = 0.f;
  const float4* f4 = reinterpret_cast<const float4*>(fLds[rl]);
#pragma unroll
  for (int i = 0; i < 16; ++i) {
    float4 fv = f4[i];
    float fd[4] = {fv.x, fv.y, fv.z, fv.w};
#pragma unroll
    for (int j = 0; j < 4; ++j) {
      int d = 4 * i + j;
      float wt = W1[d * 64 + lane];
      float wb = W1[(64 + d) * 64 + lane];
      acc_a = fmaf(fd[j], wt - wb, acc_a);
      acc_g = fmaf(fd[j], wb, acc_g);
    }
  }
  a_out[r * 64 + lane] = acc_a;
  g_out[r * 64 + lane] = acc_g;

  if (blockIdx.x < 2) {  // fused W2 swizzle (frag f = seg*4 + t)
    const int u = blockIdx.x * 256 + threadIdx.x;  // [0, 512)
    const int fr = u >> 6, ul = u & 63;
    const int seg = fr >> 2, t = fr & 3;
    const int uq = ul >> 4, uc = ul & 15;
#pragma unroll
    for (int j = 0; j < 8; ++j) {
      int d = seg * 32 + uq * 8 + j;
      w2sw[u * 8 + j] = bf16rne(W2[d * 64 + t * 16 + uc]);
    }
  }
}

// ---------------------------------------------------------------------------
// K1a v2 (round-9 verified): 512 blocks, 16 x top-4 streams, rank-by-count
// tau (bucket-ceiling, +0.5 margin).
// ---------------------------------------------------------------------------
__global__ __launch_bounds__(256, 4) void k1a_tau(
    const unsigned short* __restrict__ poshi,
    const float* __restrict__ sq, float* __restrict__ tau_g) {
  __shared__ float vw[4][16][20];         // [wave][cand][query+pad], 5 KiB
  __shared__ float sqcLds[SAMPLE];        // 4 KiB
  __shared__ unsigned topLds[16][4][17];  // [stream][k][query+pad], 4.25 KiB
  const int lane = threadIdx.x & 63;
  const int w = threadIdx.x >> 6;
  const int qbase = blockIdx.x * QT1A;
  const int col = lane & 15;
  const int quad = lane >> 4;
  const int dimOff = quad * 8;

  for (int i = threadIdx.x; i < SAMPLE; i += 256) sqcLds[i] = sq[i];

  bf16x8 A0 = *(const bf16x8*)(poshi + (size_t)(qbase + col) * 64 + dimOff);
  bf16x8 A1 = *(const bf16x8*)(poshi + (size_t)(qbase + col) * 64 + dimOff + 32);
  __syncthreads();  // sqcLds ready

  const f32x4 zf = {0.f, 0.f, 0.f, 0.f};
  float bd[4];
#pragma unroll
  for (int k = 0; k < 4; ++k) bd[k] = FLT_MAX;

  bf16x8 Bh0 = *(const bf16x8*)(poshi + (size_t)(w * 16 + col) * 64 + dimOff);
  bf16x8 Bh1 = *(const bf16x8*)(poshi + (size_t)(w * 16 + col) * 64 + dimOff + 32);
  for (int c0 = 0; c0 < SAMPLE; c0 += 64) {
    const int nc0 = (c0 + 64 < SAMPLE) ? c0 + 64 : c0;
    bf16x8 Nh0 = *(const bf16x8*)(poshi + (size_t)(nc0 + w * 16 + col) * 64 + dimOff);
    bf16x8 Nh1 = *(const bf16x8*)(poshi + (size_t)(nc0 + w * 16 + col) * 64 + dimOff + 32);

    f32x4 acc = zf;
    acc = __builtin_amdgcn_mfma_f32_16x16x32_bf16(A0, Bh0, acc, 0, 0, 0);
    acc = __builtin_amdgcn_mfma_f32_16x16x32_bf16(A1, Bh1, acc, 0, 0, 0);

    const float sqcv = sqcLds[c0 + w * 16 + col] + 256.0f;
    float4 v4;
    v4.x = fmaf(-2.f, acc[0], sqcv);
    v4.y = fmaf(-2.f, acc[1], sqcv);
    v4.z = fmaf(-2.f, acc[2], sqcv);
    v4.w = fmaf(-2.f, acc[3], sqcv);
    *reinterpret_cast<float4*>(&vw[w][col][quad * 4]) = v4;  // [cand][query]
    __builtin_amdgcn_wave_barrier();  // wave-private region, lockstep
#pragma unroll
    for (int i = 0; i < 4; ++i) {
      float cd = vw[w][quad * 4 + i][col];  // stream (w,quad): cands quad*4+i
#pragma unroll
      for (int k = 0; k < 4; ++k) {  // branch-free sorted insert (top-4)
        float lo = fminf(cd, bd[k]);
        cd = fmaxf(cd, bd[k]);
        bd[k] = lo;
      }
    }
    __builtin_amdgcn_wave_barrier();
    Bh0 = Nh0; Bh1 = Nh1;
  }

  // post packed keys: unique id = (stream<<2)|k in the low 13 bits
  {
    const int stream = w * 4 + quad;
#pragma unroll
    for (int k = 0; k < 4; ++k) {
      unsigned fb = __float_as_uint(bd[k]);
      topLds[stream][k][col] =
          (fb & 0xFFFFE000u) | (unsigned)(stream << 2) | (unsigned)k;
    }
  }
  __syncthreads();

  // tau = kept-20th via rank-by-counting (16 streams x 16 queries = 256 thr)
  {
    const int g = threadIdx.x >> 4;   // stream
    const int l = threadIdx.x & 15;   // query
    unsigned mk[4];
#pragma unroll
    for (int k = 0; k < 4; ++k) mk[k] = topLds[g][k][l];
    int rk[4] = {0, 0, 0, 0};
#pragma unroll
    for (int st = 0; st < 16; ++st) {
#pragma unroll
      for (int i = 0; i < 4; ++i) {
        unsigned v = topLds[st][i][l];
#pragma unroll
        for (int k = 0; k < 4; ++k) rk[k] += (v < mk[k]) ? 1 : 0;
      }
    }
#pragma unroll
    for (int k = 0; k < 4; ++k) {
      if (rk[k] == KNN - 1)  // unique rank-19 key -> single writer per query
        tau_g[qbase + l] =
            __uint_as_float((mk[k] & 0xFFFFE000u) + 0x2000u) + 0.5f;
    }
  }
}

// ---------------------------------------------------------------------------
// K1b v10 (round-4/10/12 verified): QT1B=64 -> 1024 blocks x 4 waves,
// VGPR 80, no spills. QT1B=32 (v11) regressed — do not re-split.
// ---------------------------------------------------------------------------
__global__ __launch_bounds__(256, 4) void k1b_collect(
    const unsigned short* __restrict__ poshi,
    const float* __restrict__ sq, const float* __restrict__ tau_g,
    unsigned* __restrict__ list, unsigned* __restrict__ cnt_ws) {
  __shared__ float sqcLds[CPB];      // 4 KiB
  __shared__ float tauLds[QT1B];
  __shared__ unsigned cntLds[QT1B];

  const int lane = threadIdx.x & 63;
  const int w = threadIdx.x >> 6;    // 0..3
  const int qbase = blockIdx.x * QT1B;
  const int cbase = blockIdx.y * CPB;
  const int col = lane & 15;
  const int quad = lane >> 4;
  const int dimOff = quad * 8;

  for (int i = threadIdx.x; i < CPB; i += 256) sqcLds[i] = sq[cbase + i];
  if (threadIdx.x < QT1B) {
    tauLds[threadIdx.x] = tau_g[qbase + threadIdx.x];
    cntLds[threadIdx.x] = 0;
  }

  // A-fragments: 4 groups of 16 queries (loaded once, reused for 16 stripes)
  bf16x8 Ahi[4][2];
#pragma unroll
  for (int s = 0; s < 4; ++s) {
    int row = qbase + s * 16 + col;
    Ahi[s][0] = *(const bf16x8*)(poshi + (size_t)row * 64 + dimOff);
    Ahi[s][1] = *(const bf16x8*)(poshi + (size_t)row * 64 + dimOff + 32);
  }
  __syncthreads();

  float tau_l[4][4];
#pragma unroll
  for (int s = 0; s < 4; ++s)
#pragma unroll
    for (int r = 0; r < 4; ++r) tau_l[s][r] = tauLds[s * 16 + quad * 4 + r];

  const f32x4 zf = {0.f, 0.f, 0.f, 0.f};
  bf16x8 Bh0 = *(const bf16x8*)(poshi + (size_t)(cbase + w * 16 + col) * 64 + dimOff);
  bf16x8 Bh1 = *(const bf16x8*)(poshi + (size_t)(cbase + w * 16 + col) * 64 + dimOff + 32);
  for (int c0 = 0; c0 < CPB; c0 += 64) {
    const int nc0 = (c0 + 64 < CPB) ? c0 + 64 : c0;
    bf16x8 Nh0 = *(const bf16x8*)(poshi + (size_t)(cbase + nc0 + w * 16 + col) * 64 + dimOff);
    bf16x8 Nh1 = *(const bf16x8*)(poshi + (size_t)(cbase + nc0 + w * 16 + col) * 64 + dimOff + 32);

    f32x4 acc[4] = {zf, zf, zf, zf};
#pragma unroll
    for (int s = 0; s < 4; ++s) {
      acc[s] = __builtin_amdgcn_mfma_f32_16x16x32_bf16(Ahi[s][0], Bh0, acc[s], 0, 0, 0);
      acc[s] = __builtin_amdgcn_mfma_f32_16x16x32_bf16(Ahi[s][1], Bh1, acc[s], 0, 0, 0);
    }
    const int candRow = cbase + c0 + w * 16 + col;
    const float sqcv = sqcLds[c0 + w * 16 + col] + 256.0f;
#pragma unroll
    for (int s = 0; s < 4; ++s) {
#pragma unroll
      for (int r = 0; r < 4; ++r) {
        float val = fmaf(-2.f, acc[s][r], sqcv);
        const int qrow = s * 16 + quad * 4 + r;  // D row = quad*4+reg
        if (val <= tau_l[s][r]) {  // ~2% of lanes
          unsigned slot = atomicAdd(&cntLds[qrow], 1u);
          if (slot < CAP)
            list[(size_t)(blockIdx.y * CAP + slot) * M_TOTAL + qbase + qrow] =
                (__float_as_uint(val) & 0xFFFFE000u) | (unsigned)candRow;
        }
      }
    }
    Bh0 = Nh0; Bh1 = Nh1;
  }
  __syncthreads();
  if (threadIdx.x < QT1B) {
    unsigned c = cntLds[threadIdx.x];
    cnt_ws[blockIdx.y * M_TOTAL + qbase + threadIdx.x] = c > CAP ? CAP : c;
  }
}

// ---------------------------------------------------------------------------
// K2ab v6 (round-12 verified best): 16 q x 16 slices (8 partitions x 2
// halves), grid 512; parallel rank-by-counting merges with exact T
// semantics; phase 1 stashes keys in kLds (33-word padded rows), phase 3
// rescans from LDS. v7 (8 q x 32 slices) regressed: phase-2b rank cost is
// LINEAR in slice count (2048 compares/thr) + halved coalescing. Do not
// re-split.
// ---------------------------------------------------------------------------
__global__ __launch_bounds__(256) void k2ab(
    const float* __restrict__ pos, const float* __restrict__ sq,
    const unsigned* __restrict__ list, const unsigned* __restrict__ cnt_ws,
    const float* __restrict__ a_in, const float* __restrict__ g_in,
    const unsigned short* __restrict__ w2sw, const float* __restrict__ b2,
    float* __restrict__ out) {
  __shared__ unsigned kLds[KSL][QT2][HCAP + 1];       // scanned keys, 33 KiB
  __shared__ unsigned topLds[KSL][QT2][9];            // kept keys, 9 KiB
  __shared__ unsigned cntSl[KSL][QT2];                // 1 KiB
  __shared__ unsigned TLds[QT2];
  __shared__ unsigned ccnt[QT2];
  __shared__ unsigned candLds[QT2][GCAP];             // 2.5 KiB
  __shared__ unsigned long long rrLds[KSL][QT2][4];   // 3 used + pad, 8 KiB
  __shared__ int nbrLds[QT2][KNN];                    // 1.25 KiB

  const int l = threadIdx.x & 15;    // query lane 0..15
  const int s2 = threadIdx.x >> 4;   // slice 0..15
  const int sp = s2 >> 1;            // partition 0..7
  const int hf = s2 & 1;             // half of the slot range
  const int q = blockIdx.x * QT2 + l;

  // ---- phase 1: per-slice top-8 over this half's keys; stash keys in LDS --
  unsigned bd[8];
#pragma unroll
  for (int k = 0; k < 8; ++k) bd[k] = 0xFFFFFFFFu;
  const unsigned c = cnt_ws[sp * M_TOTAL + q];
  const unsigned ch = (c > (unsigned)hf) ? ((c - (unsigned)hf + 1u) >> 1) : 0u;
  const unsigned* base = list + (size_t)(sp * CAP) * M_TOTAL + q;
  for (unsigned sl0 = 0; sl0 < ch; sl0 += 8) {
    unsigned kk[8];
#pragma unroll
    for (int j = 0; j < 8; ++j) {
      unsigned slj = sl0 + j;
      unsigned eff = slj < ch ? slj : 0u;          // safe: ch>0 inside loop
      kk[j] = base[(size_t)(hf + 2u * eff) * M_TOTAL];
    }
#pragma unroll
    for (int j = 0; j < 8; ++j) {
      unsigned cd;
      if (sl0 + j < ch) {
        kLds[s2][l][sl0 + j] = kk[j];  // stash for phase 3 (same thread)
        cd = kk[j];
      } else {
        cd = 0xFFFFFFFFu;
      }
#pragma unroll
      for (int k = 0; k < 8; ++k) {
        unsigned lo = cd < bd[k] ? cd : bd[k];
        cd = cd < bd[k] ? bd[k] : cd;
        bd[k] = lo;
      }
    }
  }
#pragma unroll
  for (int k = 0; k < 8; ++k) topLds[s2][l][k] = bd[k];
  cntSl[s2][l] = (ch < 8u) ? ch : 8u;
  __syncthreads();

  // ---- phase 2a: baseline T (fallback), init counters ----
  if (threadIdx.x < QT2) {
    unsigned kt = 0;
#pragma unroll
    for (int st = 0; st < KSL; ++st) kt += cntSl[st][l];
    TLds[l] = (kt >= (unsigned)KNN) ? 0u : 0xFFFFFFFFu;  // overwritten below if >=20
    ccnt[l] = 0;
#pragma unroll
    for (int k = 0; k < KNN; ++k) nbrLds[l][k] = 0;  // guard (cc<20 ~impossible)
  }
  __syncthreads();

  // ---- phase 2b: T = kept-20th via rank-by-counting over 128 keys ----
  {
    int rk[8] = {0, 0, 0, 0, 0, 0, 0, 0};
#pragma unroll
    for (int st = 0; st < KSL; ++st) {
#pragma unroll
      for (int i = 0; i < 8; ++i) {
        unsigned v = topLds[st][l][i];
#pragma unroll
        for (int k = 0; k < 8; ++k) rk[k] += (v < bd[k]) ? 1 : 0;
      }
    }
#pragma unroll
    for (int k = 0; k < 8; ++k) {
      if (bd[k] != 0xFFFFFFFFu && rk[k] == KNN - 1)
        TLds[l] = (bd[k] >> 13) + 3;  // unique rank-19 key -> single writer
    }
  }
  __syncthreads();

  // ---- phase 3: rescan this half's keys FROM LDS, collect guard set ----
  const unsigned T = TLds[l];
  for (unsigned j = 0; j < ch; ++j) {
    unsigned key = kLds[s2][l][j];
    if ((key >> 13) <= T) {
      unsigned pos_ = atomicAdd(&ccnt[l], 1u);
      if (pos_ < GCAP) candLds[l][pos_] = key & 0x1FFFu;
    }
  }
  __syncthreads();

  // ---- phase 4: exact fp32 d2 re-rank; sorted-3 per thread ----
  const int cc = min(ccnt[l], (unsigned)GCAP);
  const float sqq = sq[q];
  const float4* qp4 = reinterpret_cast<const float4*>(pos + (size_t)q * 64);
  unsigned long long kb[3];
#pragma unroll
  for (int j = 0; j < 3; ++j) kb[j] = ~0ull;
  for (int j = s2; j < cc; j += KSL) {  // <= ceil(40/16) = 3 candidates
    const unsigned idx = candLds[l][j];
    const float4* cp4 = reinterpret_cast<const float4*>(pos + (size_t)idx * 64);
    float d0 = 0.f, d1 = 0.f, d2 = 0.f, d3 = 0.f;
#pragma unroll
    for (int t = 0; t < 16; ++t) {
      float4 cv = cp4[t];
      float4 qv = qp4[t];  // L1/L2-hot
      d0 = fmaf(cv.x, qv.x, d0);
      d1 = fmaf(cv.y, qv.y, d1);
      d2 = fmaf(cv.z, qv.z, d2);
      d3 = fmaf(cv.w, qv.w, d3);
    }
    float dot = (d0 + d1) + (d2 + d3);
    float dd = fmaxf(fmaf(-2.f, dot, sqq + sq[idx]), 0.f);
    unsigned long long cd = ((unsigned long long)__float_as_uint(dd) << 32) | idx;
#pragma unroll
    for (int k = 0; k < 3; ++k) {  // sorted-3 insert (tie -> smaller idx)
      unsigned long long lo = cd < kb[k] ? cd : kb[k];
      cd = cd < kb[k] ? kb[k] : cd;
      kb[k] = lo;
    }
  }
#pragma unroll
  for (int j = 0; j < 3; ++j) rrLds[s2][l][j] = kb[j];
  __syncthreads();

  // ---- rank-by-counting top-20 placement over 48 exact keys ----
  {
    int rk[3] = {0, 0, 0};
#pragma unroll
    for (int st = 0; st < KSL; ++st) {
#pragma unroll
      for (int i = 0; i < 3; ++i) {
        unsigned long long v = rrLds[st][l][i];
#pragma unroll
        for (int j = 0; j < 3; ++j) rk[j] += (v < kb[j]) ? 1 : 0;
      }
    }
#pragma unroll
    for (int j = 0; j < 3; ++j) {
      if (kb[j] != ~0ull && rk[j] < KNN)
        nbrLds[l][rk[j]] = (int)(unsigned)(kb[j] & 0xFFFFFFFFu);
    }
  }
  __syncthreads();

  // ---- phase 5: MLP + max-agg via MFMA, 4 waves x 4 rounds (16 queries) ----
  const int lane = threadIdx.x & 63;
  const int wv = threadIdx.x >> 6;
  const int col = lane & 15;
  const int quad = lane >> 4;

  bf16x8 Bf[8];
#pragma unroll
  for (int f = 0; f < 8; ++f)
    Bf[f] = *(const bf16x8*)(w2sw + ((size_t)f * 64 + lane) * 8);
  const float bias = b2[lane];

  for (int t = 0; t < 4; ++t) {
    const int li = t * 4 + wv;                 // local query 0..15
    const int q2 = blockIdx.x * QT2 + li;
    const int n0 = nbrLds[li][col];
    const int n1 = nbrLds[li][(16 + col) % KNN];

    const f32x4 zf = {0.f, 0.f, 0.f, 0.f};
    f32x4 acc0[4] = {zf, zf, zf, zf};
    f32x4 acc1[4] = {zf, zf, zf, zf};
#pragma unroll
    for (int seg = 0; seg < 2; ++seg) {
      const int dOff = seg * 32 + quad * 8;
      const float4* ap = reinterpret_cast<const float4*>(a_in + (size_t)q2 * 64 + dOff);
      const float4* g0p = reinterpret_cast<const float4*>(g_in + (size_t)n0 * 64 + dOff);
      const float4* g1p = reinterpret_cast<const float4*>(g_in + (size_t)n1 * 64 + dOff);
      float4 aa0 = ap[0], aa1 = ap[1];
      float4 gg0 = g0p[0], gg1 = g0p[1];
      float4 hh0 = g1p[0], hh1 = g1p[1];
      float av[8] = {aa0.x, aa0.y, aa0.z, aa0.w, aa1.x, aa1.y, aa1.z, aa1.w};
      float g0v[8] = {gg0.x, gg0.y, gg0.z, gg0.w, gg1.x, gg1.y, gg1.z, gg1.w};
      float g1v[8] = {hh0.x, hh0.y, hh0.z, hh0.w, hh1.x, hh1.y, hh1.z, hh1.w};
      bf16x8 A0, A1;
#pragma unroll
      for (int j = 0; j < 8; ++j) {
        A0[j] = (short)bf16rne(fmaxf(av[j] + g0v[j], 0.f));
        A1[j] = (short)bf16rne(fmaxf(av[j] + g1v[j], 0.f));
      }
#pragma unroll
      for (int tt = 0; tt < 4; ++tt) {
        acc0[tt] = __builtin_amdgcn_mfma_f32_16x16x32_bf16(A0, Bf[seg * 4 + tt], acc0[tt], 0, 0, 0);
        acc1[tt] = __builtin_amdgcn_mfma_f32_16x16x32_bf16(A1, Bf[seg * 4 + tt], acc1[tt], 0, 0, 0);
      }
    }
    float res = 0.f;
#pragma unroll
    for (int tt = 0; tt < 4; ++tt) {
      float m = fmaxf(fmaxf(fmaxf(acc0[tt][0], acc1[tt][0]), fmaxf(acc0[tt][1], acc1[tt][1])),
                      fmaxf(fmaxf(acc0[tt][2], acc1[tt][2]), fmaxf(acc0[tt][3], acc1[tt][3])));
      m = fmaxf(m, __shfl_xor(m, 16, 64));
      m = fmaxf(m, __shfl_xor(m, 32, 64));
      res = (quad == tt) ? m : res;  // o = tt*16+col == lane iff quad==tt
    }
    out[(size_t)q2 * 64 + lane] = res + bias;
  }
}

// ---------------------------------------------------------------------------
extern "C" void kernel_launch(void* const* d_in, const int* in_sizes, int n_in,
                              void* d_out, int out_size, void* d_ws, size_t ws_size,
                              hipStream_t stream) {
  const float* pos = (const float*)d_in[0];
  const float* feat = (const float*)d_in[1];
  const float* W1 = (const float*)d_in[2];
  const float* b1 = (const float*)d_in[3];
  const float* W2 = (const float*)d_in[4];
  const float* b2 = (const float*)d_in[5];
  float* out = (float*)d_out;

  // ws layout (bytes), total ~23.3 MiB:
  //   sq    @ 0         32 KiB
  //   a     @ 32768     2 MiB
  //   g     @ 2129920   2 MiB
  //   poshi @ 4227072   1 MiB
  //   w2sw  @ 6324224   8 KiB
  //   list  @ 6332416   16 MiB  (512 slots x 8192 queries, transposed u32 keys)
  //   cnt   @ 23109632  256 KiB (8 x 8192, transposed)
  //   tau   @ 23633920  32 KiB
  char* ws = (char*)d_ws;
  float* sq = (float*)ws;
  float* a = (float*)(ws + 32768);
  float* g = (float*)(ws + 2129920);
  unsigned short* poshi = (unsigned short*)(ws + 4227072);
  unsigned short* w2sw = (unsigned short*)(ws + 6324224);
  unsigned* list = (unsigned*)(ws + 6332416);
  unsigned* cnt_ws = (unsigned*)(ws + 23109632);
  float* tau_g = (float*)(ws + 23633920);

  k0_pre<<<M_TOTAL / 4, 256, 0, stream>>>(pos, feat, W1, b1, W2, sq, a, g, poshi, w2sw);
  k1a_tau<<<M_TOTAL / QT1A, 256, 0, stream>>>(poshi, sq, tau_g);
  k1b_collect<<<dim3(M_TOTAL / QT1B, PPART), 256, 0, stream>>>(poshi, sq, tau_g, list, cnt_ws);
  k2ab<<<M_TOTAL / QT2, 256, 0, stream>>>(pos, sq, list, cnt_ws, a, g, w2sw, b2, out);
}